// Round 4
// baseline (319.910 us; speedup 1.0000x reference)
//
#include <hip/hip_runtime.h>
#include <stdint.h>

#define NB 4
#define NS 16384
#define ND 192
#define NE 8
#define NT 1024
#define NKP 256
#define NI 384
#define LNEPS 1e-5f

typedef __attribute__((ext_vector_type(8))) short bf16x8;
typedef __attribute__((ext_vector_type(4))) float f32x4;

__device__ __forceinline__ unsigned short f2bf(float f){
  unsigned u = __float_as_uint(f);
  u += 0x7FFFu + ((u >> 16) & 1u);
  return (unsigned short)(u >> 16);
}
__device__ __forceinline__ float bf2f(unsigned short s){
  return __uint_as_float((unsigned)s << 16);
}

__device__ __forceinline__ f32x4 MFMA(bf16x8 a, bf16x8 b, f32x4 c){
  return __builtin_amdgcn_mfma_f32_16x16x32_bf16(a, b, c, 0, 0, 0);
}

// ---------- K1: wave-per-token: patch stats + LN + gate logits + softmax ----------
// 256 thr = 4 waves = 4 tokens. Lane owns d = {lane, lane+64, lane+128}.
// All reductions via shfl_xor butterflies; no LDS, no barriers.
__global__ __launch_bounds__(256) void k_stats(
    const float* __restrict__ x, const float* __restrict__ ln_g,
    const float* __restrict__ ln_b, const float* __restrict__ Wg,
    const float* __restrict__ Af, const float* __restrict__ cf,
    float* __restrict__ aff){
  int wv = threadIdx.x >> 6, lane = threadIdx.x & 63;
  int bt = blockIdx.x * 4 + wv;
  int b = bt >> 10, t = bt & (NT - 1);
  int th = t >> 5, tw = t & 31;
  const float* xb = x + (size_t)b * NS * ND;
  int rb = th * 512 + tw * 4;
  float s0 = 0.f, s1 = 0.f, s2 = 0.f, q0 = 0.f, q1 = 0.f, q2 = 0.f;
#pragma unroll
  for (int p = 0; p < 16; ++p){
    int srow = rb + (p >> 2) * 128 + (p & 3);
    const float* r = xb + (size_t)srow * ND;
    float f0 = r[lane], f1 = r[lane + 64], f2 = r[lane + 128];
    s0 += f0; q0 += f0 * f0;
    s1 += f1; q1 += f1 * f1;
    s2 += f2; q2 += f2 * f2;
  }
  float m0 = s0 * 0.0625f, m1 = s1 * 0.0625f, m2 = s2 * 0.0625f;
  float pv0 = q0 * 0.0625f - m0 * m0;
  float pv1 = q1 * 0.0625f - m1 * m1;
  float pv2 = q2 * 0.0625f - m2 * m2;
  // LN over the 192 means
  float msum = m0 + m1 + m2;
#pragma unroll
  for (int off = 32; off > 0; off >>= 1) msum += __shfl_xor(msum, off);
  float mu = msum * (1.f / 192.f);
  float d0 = m0 - mu, d1 = m1 - mu, d2 = m2 - mu;
  float vsum = d0 * d0 + d1 * d1 + d2 * d2;
#pragma unroll
  for (int off = 32; off > 0; off >>= 1) vsum += __shfl_xor(vsum, off);
  float inv = 1.0f / sqrtf(vsum * (1.f / 192.f) + LNEPS);
  float pl0 = d0 * inv * ln_g[lane] + ln_b[lane];
  float pl1 = d1 * inv * ln_g[lane + 64] + ln_b[lane + 64];
  float pl2 = d2 * inv * ln_g[lane + 128] + ln_b[lane + 128];
  // logits
  float part[NE];
#pragma unroll
  for (int e = 0; e < NE; ++e){
    const float* wgr = Wg + e * 384;
    const float* afr = Af + e * ND;
    part[e] = pl0 * wgr[lane] + pv0 * afr[lane]
            + pl1 * wgr[lane + 64] + pv1 * afr[lane + 64]
            + pl2 * wgr[lane + 128] + pv2 * afr[lane + 128];
  }
#pragma unroll
  for (int e = 0; e < NE; ++e)
#pragma unroll
    for (int off = 32; off > 0; off >>= 1)
      part[e] += __shfl_xor(part[e], off);
  float lg[NE];
  float mx = -1e30f;
#pragma unroll
  for (int e = 0; e < NE; ++e){ lg[e] = part[e] + cf[e]; mx = fmaxf(mx, lg[e]); }
  float se = 0.f;
#pragma unroll
  for (int e = 0; e < NE; ++e) se += __expf(lg[e] - mx);
  int el = lane & 7;
  float my = lg[0];
#pragma unroll
  for (int e = 1; e < NE; ++e) my = (el == e) ? lg[e] : my;
  if (lane < NE)
    aff[((size_t)b * NE + lane) * NT + t] = __expf(my - mx) / se;
}

// ---------- K2a: build interleaved GU weight (bf16) + down weight (bf16) ----------
// wgu[e][c][k], c = 32*g + 16*s + r  ->  (s?Wup:Wgate)[e][16*g + r][k]
__global__ void k_wconv(const float* __restrict__ wg, const float* __restrict__ wu,
                        const float* __restrict__ wd, unsigned short* __restrict__ wgu,
                        unsigned short* __restrict__ wdb){
  int i = blockIdx.x * 256 + threadIdx.x;
  if (i < NE * 768 * ND){
    int e = i / (768 * ND);
    int rem = i - e * 768 * ND;
    int c = rem / ND;
    int k = rem - c * ND;
    int g = c >> 5, s = (c >> 4) & 1, r = c & 15;
    const float* src = s ? wu : wg;
    wgu[i] = f2bf(src[((size_t)(e * NI + g * 16 + r)) * ND + k]);
  }
  if (i < NE * ND * NI){
    wdb[i] = f2bf(wd[i]);
  }
}

// ---------- K2b: fold cplx matmul into gate ----------
__global__ void k_fuse(const float* __restrict__ Wc, const float* __restrict__ Wg,
                       const float* __restrict__ bc, const float* __restrict__ bg,
                       float* __restrict__ Af, float* __restrict__ cf){
  int idx = blockIdx.x * 128 + threadIdx.x;
  if (idx < NE * ND){
    int e = idx / ND, dd = idx % ND;
    float s = 0.f;
    for (int dp = 0; dp < ND; ++dp) s += Wg[e * 384 + ND + dp] * Wc[dp * ND + dd];
    Af[idx] = s;
  }
  if (idx < NE){
    float s = bg[idx];
    for (int dp = 0; dp < ND; ++dp) s += bc[dp] * Wg[idx * 384 + ND + dp];
    cf[idx] = s;
  }
}

// ---------- K4: exact-rank top-k + inverse index ----------
__global__ __launch_bounds__(256) void k_topk(
    const float* __restrict__ aff, int* __restrict__ sidx,
    float* __restrict__ sval, float* __restrict__ twt,
    int* __restrict__ cnt, int* __restrict__ inv){
  int be = blockIdx.x;
  int b = be >> 3, e = be & 7;
  __shared__ float vals[NT];
  for (int t = threadIdx.x; t < NT; t += 256) vals[t] = aff[(size_t)be * NT + t];
  __syncthreads();
  int t0 = threadIdx.x, t1 = t0 + 256, t2 = t0 + 512, t3 = t0 + 768;
  float v0 = vals[t0], v1 = vals[t1], v2 = vals[t2], v3 = vals[t3];
  int r0 = 0, r1 = 0, r2 = 0, r3 = 0;
  for (int j = 0; j < NT; ++j){
    float vj = vals[j];
    r0 += (vj > v0) || (vj == v0 && j < t0);
    r1 += (vj > v1) || (vj == v1 && j < t1);
    r2 += (vj > v2) || (vj == v2 && j < t2);
    r3 += (vj > v3) || (vj == v3 && j < t3);
  }
  if (r0 < NKP){ sidx[be * NKP + r0] = t0; sval[be * NKP + r0] = v0; atomicAdd(&twt[b * NT + t0], v0);
                 int p = atomicAdd(&cnt[b * NT + t0], 1); inv[(b * NT + t0) * 8 + p] = (e << 16) | r0; }
  if (r1 < NKP){ sidx[be * NKP + r1] = t1; sval[be * NKP + r1] = v1; atomicAdd(&twt[b * NT + t1], v1);
                 int p = atomicAdd(&cnt[b * NT + t1], 1); inv[(b * NT + t1) * 8 + p] = (e << 16) | r1; }
  if (r2 < NKP){ sidx[be * NKP + r2] = t2; sval[be * NKP + r2] = v2; atomicAdd(&twt[b * NT + t2], v2);
                 int p = atomicAdd(&cnt[b * NT + t2], 1); inv[(b * NT + t2) * 8 + p] = (e << 16) | r2; }
  if (r3 < NKP){ sidx[be * NKP + r3] = t3; sval[be * NKP + r3] = v3; atomicAdd(&twt[b * NT + t3], v3);
                 int p = atomicAdd(&cnt[b * NT + t3], 1); inv[(b * NT + t3) * 8 + p] = (e << 16) | r3; }
}

// ---------- K6: expert FFN (bf16 MFMA) -> raw contrib (bf16) ----------
// 256 thr = 4 waves, one (b,e) x 64 rows. B-operands batch-loaded per ks with
// depth-1 prefetch so 6 (resp. 3) L2 loads are in flight under the MFMAs.
__global__ __launch_bounds__(256) void k_ffn(
    const float* __restrict__ x, const unsigned short* __restrict__ wgu,
    const unsigned short* __restrict__ wdb,
    const int* __restrict__ sidx,
    unsigned short* __restrict__ contrib){
  int be = blockIdx.x, b = be >> 3, e = be & 7;
  int tile = blockIdx.y;
  int jb = tile * 4;
  int tid = threadIdx.x, w = tid >> 6, lane = tid & 63;
  int l15 = lane & 15, l4 = lane >> 4;
  __shared__ __align__(16) unsigned short Xl[64 * 192]; // swizzled bf16
  __shared__ __align__(16) unsigned short Hl[64 * 384]; // swizzled bf16

  { // gather X: 64 rows x 192 fp32 -> bf16 swizzled (4 thr/row, 48 cols each)
    int row = tid >> 2, q = tid & 3;
    int j = jb + (row >> 4), p = row & 15;
    int t = sidx[be * NKP + j];
    int th = t >> 5, tw = t & 31;
    int srow = th * 512 + (p >> 2) * 128 + tw * 4 + (p & 3);
    const float* src = x + ((size_t)(b * NS + srow)) * ND + q * 48;
    int rbase = row * 384, rsw = (row & 7) << 4;
#pragma unroll
    for (int c = 0; c < 6; ++c){
      float4 f0 = *reinterpret_cast<const float4*>(src + c * 8);
      float4 f1 = *reinterpret_cast<const float4*>(src + c * 8 + 4);
      uint4 pk;
      pk.x = (unsigned)f2bf(f0.x) | ((unsigned)f2bf(f0.y) << 16);
      pk.y = (unsigned)f2bf(f0.z) | ((unsigned)f2bf(f0.w) << 16);
      pk.z = (unsigned)f2bf(f1.x) | ((unsigned)f2bf(f1.y) << 16);
      pk.w = (unsigned)f2bf(f1.z) | ((unsigned)f2bf(f1.w) << 16);
      int byte = rbase + (((q * 48 + c * 8) * 2) ^ rsw);
      *reinterpret_cast<uint4*>(reinterpret_cast<char*>(Xl) + byte) = pk;
    }
  }
  __syncthreads();

  // ---- GU: C = X @ Wgu^T over interleaved 768 cols, 2 passes of 384
  // per-wave B row base: all 36 loads are base + compile-time offset
#pragma unroll
  for (int np = 0; np < 2; ++np){
    const unsigned short* wb =
        wgu + ((size_t)(e * 768 + np * 384 + w * 96 + l15)) * ND + l4 * 8;
    f32x4 acc[4][6];
#pragma unroll
    for (int mt = 0; mt < 4; ++mt)
#pragma unroll
      for (int nt = 0; nt < 6; ++nt) acc[mt][nt] = f32x4{0.f, 0.f, 0.f, 0.f};

    bf16x8 bb[6];
#pragma unroll
    for (int nt = 0; nt < 6; ++nt)
      bb[nt] = *reinterpret_cast<const bf16x8*>(wb + nt * 16 * ND);
#pragma unroll
    for (int ks = 0; ks < 6; ++ks){
      bf16x8 bn[6];
      if (ks < 5){
#pragma unroll
        for (int nt = 0; nt < 6; ++nt)
          bn[nt] = *reinterpret_cast<const bf16x8*>(wb + nt * 16 * ND + (ks + 1) * 32);
      }
      bf16x8 a[4];
#pragma unroll
      for (int mt = 0; mt < 4; ++mt){
        int row = mt * 16 + l15;
        int byte = row * 384 + ((ks * 64 + l4 * 16) ^ ((row & 7) << 4));
        a[mt] = *reinterpret_cast<const bf16x8*>(reinterpret_cast<const char*>(Xl) + byte);
      }
#pragma unroll
      for (int nt = 0; nt < 6; ++nt)
#pragma unroll
        for (int mt = 0; mt < 4; ++mt)
          acc[mt][nt] = MFMA(a[mt], bb[nt], acc[mt][nt]);
      if (ks < 5){
#pragma unroll
        for (int nt = 0; nt < 6; ++nt) bb[nt] = bn[nt];
      }
    }
    // silu(G)*U -> bf16 -> swizzled Hl (nt even = gate, nt odd = up)
#pragma unroll
    for (int gp = 0; gp < 3; ++gp)
#pragma unroll
      for (int mt = 0; mt < 4; ++mt)
#pragma unroll
        for (int r = 0; r < 4; ++r){
          float g = acc[mt][2 * gp][r];
          float u = acc[mt][2 * gp + 1][r];
          float h = g * u / (1.f + __expf(-g));
          int hrow = mt * 16 + l4 * 4 + r;
          int hcol = np * 192 + w * 48 + gp * 16 + l15;
          int byte = hrow * 768 + ((hcol * 2) ^ ((hrow & 7) << 4));
          *reinterpret_cast<unsigned short*>(reinterpret_cast<char*>(Hl) + byte) = f2bf(h);
        }
  }
  __syncthreads();

  // ---- down: O = H @ Wdown^T ; wave tile 64 x 48, batch+prefetch B
  const unsigned short* db =
      wdb + ((size_t)(e * ND + w * 48 + l15)) * NI + l4 * 8;
  f32x4 ao[4][3];
#pragma unroll
  for (int mt = 0; mt < 4; ++mt)
#pragma unroll
    for (int nt = 0; nt < 3; ++nt) ao[mt][nt] = f32x4{0.f, 0.f, 0.f, 0.f};
  bf16x8 bd[3];
#pragma unroll
  for (int nt = 0; nt < 3; ++nt)
    bd[nt] = *reinterpret_cast<const bf16x8*>(db + nt * 16 * NI);
#pragma unroll
  for (int ks = 0; ks < 12; ++ks){
    bf16x8 dn[3];
    if (ks < 11){
#pragma unroll
      for (int nt = 0; nt < 3; ++nt)
        dn[nt] = *reinterpret_cast<const bf16x8*>(db + nt * 16 * NI + (ks + 1) * 32);
    }
    bf16x8 a[4];
#pragma unroll
    for (int mt = 0; mt < 4; ++mt){
      int row = mt * 16 + l15;
      int byte = row * 768 + ((ks * 64 + l4 * 16) ^ ((row & 7) << 4));
      a[mt] = *reinterpret_cast<const bf16x8*>(reinterpret_cast<const char*>(Hl) + byte);
    }
#pragma unroll
    for (int nt = 0; nt < 3; ++nt)
#pragma unroll
      for (int mt = 0; mt < 4; ++mt)
        ao[mt][nt] = MFMA(a[mt], bd[nt], ao[mt][nt]);
    if (ks < 11){
#pragma unroll
      for (int nt = 0; nt < 3; ++nt) bd[nt] = dn[nt];
    }
  }
  // ---- raw contrib store (bf16, unweighted)
#pragma unroll
  for (int mt = 0; mt < 4; ++mt){
#pragma unroll
    for (int r = 0; r < 4; ++r){
      int mrow = tile * 64 + mt * 16 + l4 * 4 + r;
      unsigned short* dst = contrib + ((size_t)be * 4096 + mrow) * ND;
#pragma unroll
      for (int nt = 0; nt < 3; ++nt){
        int dcol = w * 48 + nt * 16 + l15;
        dst[dcol] = f2bf(ao[mt][nt][r]);
      }
    }
  }
}

// ---------- K7: per-token weighted gather-sum of contributions -> out ----------
__global__ __launch_bounds__(256) void k_scatter(
    const unsigned short* __restrict__ contrib, const int* __restrict__ cnt,
    const int* __restrict__ inv, const float* __restrict__ sval,
    const float* __restrict__ twt, float* __restrict__ out){
  int bt = blockIdx.x;
  int b = bt >> 10, t = bt & (NT - 1);
  __shared__ int s_cnt;
  __shared__ int s_ent[8];
  __shared__ float s_wt[8];
  if (threadIdx.x == 0) s_cnt = cnt[bt];
  if (threadIdx.x < 8){
    int ent = inv[bt * 8 + threadIdx.x];
    s_ent[threadIdx.x] = ent;
    float tws = fmaxf(twt[bt], 1e-8f);
    int e = ent >> 16, r = ent & 0xffff;
    s_wt[threadIdx.x] = sval[((size_t)((b << 3) + e)) * NKP + r] / tws;
  }
  __syncthreads();
  int n = s_cnt;
  int p = threadIdx.x >> 4, dq = threadIdx.x & 15;
  int d0 = dq * 12;
  float acc[12];
#pragma unroll
  for (int i = 0; i < 12; ++i) acc[i] = 0.f;
  for (int i = 0; i < n; ++i){
    int ent = s_ent[i];
    int e = ent >> 16, r = ent & 0xffff;
    float wt = s_wt[i];
    const unsigned short* src = contrib +
        ((((size_t)((b * 8 + e) * NKP + r)) * 16 + p) * ND + d0);
#pragma unroll
    for (int c = 0; c < 3; ++c){
      uint2 v = *reinterpret_cast<const uint2*>(src + c * 4);
      acc[c * 4 + 0] += wt * bf2f((unsigned short)(v.x & 0xffff));
      acc[c * 4 + 1] += wt * bf2f((unsigned short)(v.x >> 16));
      acc[c * 4 + 2] += wt * bf2f((unsigned short)(v.y & 0xffff));
      acc[c * 4 + 3] += wt * bf2f((unsigned short)(v.y >> 16));
    }
  }
  int th = t >> 5, tw = t & 31;
  int srow = th * 512 + (p >> 2) * 128 + tw * 4 + (p & 3);
  float* dst = out + ((size_t)(b * NS + srow)) * ND + d0;
#pragma unroll
  for (int c = 0; c < 3; ++c){
    float4 o;
    o.x = acc[c * 4 + 0]; o.y = acc[c * 4 + 1];
    o.z = acc[c * 4 + 2]; o.w = acc[c * 4 + 3];
    *reinterpret_cast<float4*>(dst + c * 4) = o;
  }
}

extern "C" void kernel_launch(void* const* d_in, const int* in_sizes, int n_in,
                              void* d_out, int out_size, void* d_ws, size_t ws_size,
                              hipStream_t stream){
  const float* x     = (const float*)d_in[0];
  const float* ln_g  = (const float*)d_in[1];
  const float* ln_b  = (const float*)d_in[2];
  const float* Wc    = (const float*)d_in[3];
  const float* bc    = (const float*)d_in[4];
  const float* Wg    = (const float*)d_in[5];
  const float* bg    = (const float*)d_in[6];
  const float* Wgate = (const float*)d_in[7];
  const float* Wup   = (const float*)d_in[8];
  const float* Wdown = (const float*)d_in[9];
  float* out = (float*)d_out;
  (void)in_sizes; (void)n_in; (void)ws_size; (void)out_size;

  char* ws = (char*)d_ws;
  size_t o = 0;
  auto carve = [&](size_t bytes) -> char* {
    char* p = ws + o; o += (bytes + 255) & ~(size_t)255; return p;
  };
  float* aff  = (float*)carve((size_t)NB * NE * NT * 4);
  float* Af   = (float*)carve(NE * ND * 4);
  float* cf   = (float*)carve(256);
  int*   sidx = (int*)carve(NB * NE * NKP * 4);
  float* sval = (float*)carve(NB * NE * NKP * 4);
  float* twt  = (float*)carve(NB * NT * 4);
  int*   cnt  = (int*)carve(NB * NT * 4);
  int*   inv  = (int*)carve(NB * NT * 8 * 4);
  unsigned short* wgu = (unsigned short*)carve((size_t)NE * 768 * ND * 2);
  unsigned short* wdb = (unsigned short*)carve((size_t)NE * ND * NI * 2);
  unsigned short* contrib = (unsigned short*)carve((size_t)NB * NE * NKP * 16 * ND * 2);

  hipMemsetAsync(twt, 0, NB * NT * 4, stream);
  hipMemsetAsync(cnt, 0, NB * NT * 4, stream);

  k_wconv<<<(NE * 768 * ND + 255) / 256, 256, 0, stream>>>(Wgate, Wup, Wdown, wgu, wdb);
  k_fuse<<<12, 128, 0, stream>>>(Wc, Wg, bc, bg, Af, cf);
  k_stats<<<NB * NT / 4, 256, 0, stream>>>(x, ln_g, ln_b, Wg, Af, cf, aff);
  k_topk<<<NB * NE, 256, 0, stream>>>(aff, sidx, sval, twt, cnt, inv);
  dim3 gffn(NB * NE, 4096 / 64, 1);
  k_ffn<<<gffn, 256, 0, stream>>>(x, wgu, wdb, sidx, contrib);
  k_scatter<<<NB * NT, 256, 0, stream>>>(contrib, cnt, inv, sval, twt, out);
}